// Round 1
// baseline (3002.064 us; speedup 1.0000x reference)
//
#include <hip/hip_runtime.h>
#include <math.h>

#define NUM_LEVELS 16
#define TABLE_SIZE (1u << 19)

struct LevelParams {
    float scale[NUM_LEVELS];
    unsigned int res[NUM_LEVELS];
};

// One thread = one point. Encode (16 levels, 8 corners, trilinear) fully
// unrolled into registers, then 32->32->32->3 MLP with weights read via the
// scalar path (uniform addresses -> s_load; no LDS, no per-lane weight VGPRs).
__global__ __launch_bounds__(256) void mlp_tex3d_kernel(
    const float* __restrict__ texc,
    const float* __restrict__ table,
    const float* __restrict__ W0,
    const float* __restrict__ W1,
    const float* __restrict__ W2,
    float* __restrict__ out,
    int n,
    LevelParams p)
{
    int i = blockIdx.x * 256 + threadIdx.x;
    if (i >= n) return;

    const float tx = texc[3 * i + 0];
    const float ty = texc[3 * i + 1];
    const float tz = texc[3 * i + 2];

    float enc[2 * NUM_LEVELS];

#pragma unroll
    for (int l = 0; l < NUM_LEVELS; ++l) {
        const float s = p.scale[l];
        const unsigned res = p.res[l];

        // pos = texc*scale + 0.5 (separate mul+add like the reference; fp32)
        const float px = tx * s + 0.5f;
        const float py = ty * s + 0.5f;
        const float pz = tz * s + 0.5f;
        const float gx = floorf(px), gy = floorf(py), gz = floorf(pz);
        const float wx = px - gx, wy = py - gy, wz = pz - gz;
        const unsigned x0 = (unsigned)gx, y0 = (unsigned)gy, z0 = (unsigned)gz;

        const float2* __restrict__ tbl =
            (const float2*)(table + (size_t)l * (TABLE_SIZE * 2));

        float f0 = 0.f, f1 = 0.f;
#pragma unroll
        for (int c = 0; c < 8; ++c) {
            const unsigned dx = c & 1u, dy = (c >> 1) & 1u, dz = (c >> 2) & 1u;
            const unsigned xi = x0 + dx, yi = y0 + dy, zi = z0 + dz;
            unsigned idx;
            if (l < 5) {
                // dense level: res^3 <= TABLE_SIZE for levels 0..4
                idx = xi + yi * res + zi * res * res;
            } else {
                // spatial hash, PRIMES = {1, 2654435761, 805459861}, mod 2^19
                idx = (xi ^ (yi * 2654435761u) ^ (zi * 805459861u)) &
                      (TABLE_SIZE - 1u);
            }
            const float2 g = tbl[idx];
            const float w = (dx ? wx : 1.f - wx) *
                            (dy ? wy : 1.f - wy) *
                            (dz ? wz : 1.f - wz);
            f0 = fmaf(w, g.x, f0);
            f1 = fmaf(w, g.y, f1);
        }
        enc[2 * l + 0] = f0;
        enc[2 * l + 1] = f1;
    }

    // ---- MLP: h1 = relu(enc @ W0^T) ----
    float h1[32];
#pragma unroll
    for (int j = 0; j < 32; ++j) {
        float acc = 0.f;
#pragma unroll
        for (int k = 0; k < 32; ++k)
            acc = fmaf(enc[k], W0[j * 32 + k], acc);
        h1[j] = fmaxf(acc, 0.f);
    }

    // ---- h2 = relu(h1 @ W1^T) ----
    float h2[32];
#pragma unroll
    for (int j = 0; j < 32; ++j) {
        float acc = 0.f;
#pragma unroll
        for (int k = 0; k < 32; ++k)
            acc = fmaf(h1[k], W1[j * 32 + k], acc);
        h2[j] = fmaxf(acc, 0.f);
    }

    // ---- out = sigmoid(h2 @ W2^T), W2 is [3,32] ----
#pragma unroll
    for (int j = 0; j < 3; ++j) {
        float acc = 0.f;
#pragma unroll
        for (int k = 0; k < 32; ++k)
            acc = fmaf(h2[k], W2[j * 32 + k], acc);
        out[3 * i + j] = 1.f / (1.f + __expf(-acc));
    }
}

extern "C" void kernel_launch(void* const* d_in, const int* in_sizes, int n_in,
                              void* d_out, int out_size, void* d_ws, size_t ws_size,
                              hipStream_t stream) {
    const float* texc  = (const float*)d_in[0];
    const float* table = (const float*)d_in[1];
    const float* W0    = (const float*)d_in[2];
    const float* W1    = (const float*)d_in[3];
    const float* W2    = (const float*)d_in[4];
    float* out = (float*)d_out;

    const int n = in_sizes[0] / 3;

    // Per-level scale/res computed on host in double, matching the numpy
    // reference: scale = exp2(lvl * log2(PER_LEVEL_SCALE)) * 16 - 1,
    // log2(PER_LEVEL_SCALE) = 8/15. res = ceil(scale) + 1.
    LevelParams p;
    const double log2pls = log(4096.0 / 16.0) / 15.0 / log(2.0);
    for (int l = 0; l < NUM_LEVELS; ++l) {
        const double sc = exp2((double)l * log2pls) * 16.0 - 1.0;
        p.scale[l] = (float)sc;
        p.res[l] = (unsigned)(ceil(sc) + 1.0);
    }

    const int blocks = (n + 255) / 256;
    mlp_tex3d_kernel<<<blocks, 256, 0, stream>>>(texc, table, W0, W1, W2, out,
                                                 n, p);
}

// Round 3
// 1712.166 us; speedup vs baseline: 1.7534x; 1.7534x over previous
//
#include <hip/hip_runtime.h>
#include <math.h>

#define NUM_LEVELS 16
#define N_DENSE 5              // levels 0..4 are dense (res^3 <= 2^19)
#define N_HASH (NUM_LEVELS - N_DENSE)
#define TABLE_SIZE (1u << 19)

struct DenseParams {
    float scale[N_DENSE];
    unsigned int res[N_DENSE];
};

struct AllParams {
    float scale[NUM_LEVELS];
    unsigned int res[NUM_LEVELS];
};

// bf16 round-to-nearest-even, returns low-16 bits.
static __device__ __forceinline__ unsigned bf16_bits(float f) {
    const unsigned u = __builtin_bit_cast(unsigned, f);
    const unsigned rnd = 0x7fffu + ((u >> 16) & 1u);
    return (u + rnd) >> 16;
}

// ---------------------------------------------------------------------------
// Per-hashed-level encode. One dispatch per level so the level's 4 MiB table
// is the only hot working set -> L2-resident per XCD. texc loads and enc
// stores are nontemporal to avoid polluting L2.
// Output: packed bf16x2 per point at enc_out[i].
// ---------------------------------------------------------------------------
__global__ __launch_bounds__(256) void hashed_encode_kernel(
    const float* __restrict__ texc,
    const float2* __restrict__ tbl,          // this level's table [2^19]
    unsigned int* __restrict__ enc_out,      // [n] packed bf16x2
    int n, float scale)
{
    int i = blockIdx.x * 256 + threadIdx.x;
    if (i >= n) return;

    const float tx = __builtin_nontemporal_load(texc + 3 * i + 0);
    const float ty = __builtin_nontemporal_load(texc + 3 * i + 1);
    const float tz = __builtin_nontemporal_load(texc + 3 * i + 2);

    const float px = tx * scale + 0.5f;
    const float py = ty * scale + 0.5f;
    const float pz = tz * scale + 0.5f;
    const float gx = floorf(px), gy = floorf(py), gz = floorf(pz);
    const float wx = px - gx, wy = py - gy, wz = pz - gz;
    const unsigned x0 = (unsigned)gx, y0 = (unsigned)gy, z0 = (unsigned)gz;

    float f0 = 0.f, f1 = 0.f;
#pragma unroll
    for (int c = 0; c < 8; ++c) {
        const unsigned dx = c & 1u, dy = (c >> 1) & 1u, dz = (c >> 2) & 1u;
        const unsigned idx =
            ((x0 + dx) ^ ((y0 + dy) * 2654435761u) ^ ((z0 + dz) * 805459861u))
            & (TABLE_SIZE - 1u);
        const float2 g = tbl[idx];
        const float w = (dx ? wx : 1.f - wx) *
                        (dy ? wy : 1.f - wy) *
                        (dz ? wz : 1.f - wz);
        f0 = fmaf(w, g.x, f0);
        f1 = fmaf(w, g.y, f1);
    }

    const unsigned packed = bf16_bits(f0) | (bf16_bits(f1) << 16);
    __builtin_nontemporal_store(packed, enc_out + i);
}

// ---------------------------------------------------------------------------
// Final fused kernel: dense levels 0..4 (tables total ~4.2 MiB, L2-resident)
// + unpack the 11 hashed-level bf16 features + 32->32->32->3 MLP + sigmoid.
// ---------------------------------------------------------------------------
__global__ __launch_bounds__(256) void dense_mlp_kernel(
    const float* __restrict__ texc,
    const float* __restrict__ table,
    const unsigned int* __restrict__ enc_ws, // [N_HASH][n] packed bf16x2
    const float* __restrict__ W0,
    const float* __restrict__ W1,
    const float* __restrict__ W2,
    float* __restrict__ out,
    int n, DenseParams p)
{
    int i = blockIdx.x * 256 + threadIdx.x;
    if (i >= n) return;

    float enc[2 * NUM_LEVELS];

    // Hashed features: 11 coalesced 4 B stream reads (issue early).
#pragma unroll
    for (int l = 0; l < N_HASH; ++l) {
        const unsigned v =
            __builtin_nontemporal_load(enc_ws + (size_t)l * n + i);
        enc[2 * (l + N_DENSE) + 0] = __builtin_bit_cast(float, v << 16);
        enc[2 * (l + N_DENSE) + 1] =
            __builtin_bit_cast(float, v & 0xffff0000u);
    }

    const float tx = __builtin_nontemporal_load(texc + 3 * i + 0);
    const float ty = __builtin_nontemporal_load(texc + 3 * i + 1);
    const float tz = __builtin_nontemporal_load(texc + 3 * i + 2);

    // Dense levels 0..4.
#pragma unroll
    for (int l = 0; l < N_DENSE; ++l) {
        const float s = p.scale[l];
        const unsigned res = p.res[l];
        const float px = tx * s + 0.5f;
        const float py = ty * s + 0.5f;
        const float pz = tz * s + 0.5f;
        const float gx = floorf(px), gy = floorf(py), gz = floorf(pz);
        const float wx = px - gx, wy = py - gy, wz = pz - gz;
        const unsigned x0 = (unsigned)gx, y0 = (unsigned)gy, z0 = (unsigned)gz;

        const float2* __restrict__ tbl =
            (const float2*)(table + (size_t)l * (TABLE_SIZE * 2));

        float f0 = 0.f, f1 = 0.f;
#pragma unroll
        for (int c = 0; c < 8; ++c) {
            const unsigned dx = c & 1u, dy = (c >> 1) & 1u, dz = (c >> 2) & 1u;
            const unsigned idx =
                (x0 + dx) + (y0 + dy) * res + (z0 + dz) * res * res;
            const float2 g = tbl[idx];
            const float w = (dx ? wx : 1.f - wx) *
                            (dy ? wy : 1.f - wy) *
                            (dz ? wz : 1.f - wz);
            f0 = fmaf(w, g.x, f0);
            f1 = fmaf(w, g.y, f1);
        }
        enc[2 * l + 0] = f0;
        enc[2 * l + 1] = f1;
    }

    // ---- MLP (weights via uniform/scalar loads) ----
    float h1[32];
#pragma unroll
    for (int j = 0; j < 32; ++j) {
        float acc = 0.f;
#pragma unroll
        for (int k = 0; k < 32; ++k)
            acc = fmaf(enc[k], W0[j * 32 + k], acc);
        h1[j] = fmaxf(acc, 0.f);
    }

    float h2[32];
#pragma unroll
    for (int j = 0; j < 32; ++j) {
        float acc = 0.f;
#pragma unroll
        for (int k = 0; k < 32; ++k)
            acc = fmaf(h1[k], W1[j * 32 + k], acc);
        h2[j] = fmaxf(acc, 0.f);
    }

#pragma unroll
    for (int j = 0; j < 3; ++j) {
        float acc = 0.f;
#pragma unroll
        for (int k = 0; k < 32; ++k)
            acc = fmaf(h2[k], W2[j * 32 + k], acc);
        out[3 * i + j] = 1.f / (1.f + __expf(-acc));
    }
}

// ---------------------------------------------------------------------------
// Fallback: monolithic kernel (round-1 version) if ws is too small.
// ---------------------------------------------------------------------------
__global__ __launch_bounds__(256) void mono_kernel(
    const float* __restrict__ texc,
    const float* __restrict__ table,
    const float* __restrict__ W0,
    const float* __restrict__ W1,
    const float* __restrict__ W2,
    float* __restrict__ out,
    int n, AllParams p)
{
    int i = blockIdx.x * 256 + threadIdx.x;
    if (i >= n) return;
    const float tx = texc[3 * i + 0];
    const float ty = texc[3 * i + 1];
    const float tz = texc[3 * i + 2];
    float enc[2 * NUM_LEVELS];
#pragma unroll
    for (int l = 0; l < NUM_LEVELS; ++l) {
        const float s = p.scale[l];
        const unsigned res = p.res[l];
        const float px = tx * s + 0.5f;
        const float py = ty * s + 0.5f;
        const float pz = tz * s + 0.5f;
        const float gx = floorf(px), gy = floorf(py), gz = floorf(pz);
        const float wx = px - gx, wy = py - gy, wz = pz - gz;
        const unsigned x0 = (unsigned)gx, y0 = (unsigned)gy, z0 = (unsigned)gz;
        const float2* __restrict__ tbl =
            (const float2*)(table + (size_t)l * (TABLE_SIZE * 2));
        float f0 = 0.f, f1 = 0.f;
#pragma unroll
        for (int c = 0; c < 8; ++c) {
            const unsigned dx = c & 1u, dy = (c >> 1) & 1u, dz = (c >> 2) & 1u;
            const unsigned xi = x0 + dx, yi = y0 + dy, zi = z0 + dz;
            unsigned idx;
            if (l < N_DENSE) idx = xi + yi * res + zi * res * res;
            else idx = (xi ^ (yi * 2654435761u) ^ (zi * 805459861u)) &
                       (TABLE_SIZE - 1u);
            const float2 g = tbl[idx];
            const float w = (dx ? wx : 1.f - wx) *
                            (dy ? wy : 1.f - wy) *
                            (dz ? wz : 1.f - wz);
            f0 = fmaf(w, g.x, f0);
            f1 = fmaf(w, g.y, f1);
        }
        enc[2 * l + 0] = f0;
        enc[2 * l + 1] = f1;
    }
    float h1[32];
#pragma unroll
    for (int j = 0; j < 32; ++j) {
        float acc = 0.f;
#pragma unroll
        for (int k = 0; k < 32; ++k) acc = fmaf(enc[k], W0[j * 32 + k], acc);
        h1[j] = fmaxf(acc, 0.f);
    }
    float h2[32];
#pragma unroll
    for (int j = 0; j < 32; ++j) {
        float acc = 0.f;
#pragma unroll
        for (int k = 0; k < 32; ++k) acc = fmaf(h1[k], W1[j * 32 + k], acc);
        h2[j] = fmaxf(acc, 0.f);
    }
#pragma unroll
    for (int j = 0; j < 3; ++j) {
        float acc = 0.f;
#pragma unroll
        for (int k = 0; k < 32; ++k) acc = fmaf(h2[k], W2[j * 32 + k], acc);
        out[3 * i + j] = 1.f / (1.f + __expf(-acc));
    }
}

extern "C" void kernel_launch(void* const* d_in, const int* in_sizes, int n_in,
                              void* d_out, int out_size, void* d_ws, size_t ws_size,
                              hipStream_t stream) {
    const float* texc  = (const float*)d_in[0];
    const float* table = (const float*)d_in[1];
    const float* W0    = (const float*)d_in[2];
    const float* W1    = (const float*)d_in[3];
    const float* W2    = (const float*)d_in[4];
    float* out = (float*)d_out;

    const int n = in_sizes[0] / 3;
    const int blocks = (n + 255) / 256;

    // Per-level scale/res, host-side double to match numpy:
    // scale = exp2(l * log2(PER_LEVEL_SCALE)) * 16 - 1; res = ceil(scale)+1.
    AllParams ap;
    const double log2pls = log(4096.0 / 16.0) / 15.0 / log(2.0);
    for (int l = 0; l < NUM_LEVELS; ++l) {
        const double sc = exp2((double)l * log2pls) * 16.0 - 1.0;
        ap.scale[l] = (float)sc;
        ap.res[l] = (unsigned)(ceil(sc) + 1.0);
    }

    const size_t need = (size_t)N_HASH * (size_t)n * 4u;
    if (ws_size >= need) {
        unsigned int* enc_ws = (unsigned int*)d_ws;
        for (int l = N_DENSE; l < NUM_LEVELS; ++l) {
            const float2* tbl =
                (const float2*)(table + (size_t)l * (TABLE_SIZE * 2));
            hashed_encode_kernel<<<blocks, 256, 0, stream>>>(
                texc, tbl, enc_ws + (size_t)(l - N_DENSE) * n, n, ap.scale[l]);
        }
        DenseParams dp;
        for (int l = 0; l < N_DENSE; ++l) {
            dp.scale[l] = ap.scale[l];
            dp.res[l] = ap.res[l];
        }
        dense_mlp_kernel<<<blocks, 256, 0, stream>>>(
            texc, table, enc_ws, W0, W1, W2, out, n, dp);
    } else {
        mono_kernel<<<blocks, 256, 0, stream>>>(texc, table, W0, W1, W2, out,
                                                n, ap);
    }
}

// Round 4
// 1485.649 us; speedup vs baseline: 2.0207x; 1.1525x over previous
//
#include <hip/hip_runtime.h>
#include <math.h>

#define NUM_LEVELS 16
#define N_DENSE 5
#define N_HASH (NUM_LEVELS - N_DENSE)
#define TABLE_SIZE (1u << 19)
#define TMASK (TABLE_SIZE - 1u)

typedef float f32x4 __attribute__((ext_vector_type(4)));
typedef float f32x2 __attribute__((ext_vector_type(2)));
typedef short s16x8 __attribute__((ext_vector_type(8)));

struct HashParams { float scale[N_HASH]; };
struct DenseParams { float scale[N_DENSE]; unsigned res[N_DENSE]; };
struct AllParams { float scale[NUM_LEVELS]; unsigned res[NUM_LEVELS]; };

static __device__ __forceinline__ unsigned bf16_bits(float f) {
    const unsigned u = __builtin_bit_cast(unsigned, f);
    return (u + (0x7fffu + ((u >> 16) & 1u))) >> 16;
}
static __device__ __forceinline__ short bf16s(float f) { return (short)bf16_bits(f); }
static __device__ __forceinline__ float bflo(unsigned v) { return __builtin_bit_cast(float, v << 16); }
static __device__ __forceinline__ float bfhi(unsigned v) { return __builtin_bit_cast(float, v & 0xffff0000u); }

// 8 consecutive fp32 -> bf16x8 (for layer-0 B fragments: B[k][n]=W0[n][k])
static __device__ __forceinline__ s16x8 packW8(const float* __restrict__ p) {
    const f32x4 a = *(const f32x4*)p;
    const f32x4 b = *(const f32x4*)(p + 4);
    s16x8 v;
    v[0] = bf16s(a.x); v[1] = bf16s(a.y); v[2] = bf16s(a.z); v[3] = bf16s(a.w);
    v[4] = bf16s(b.x); v[5] = bf16s(b.y); v[6] = bf16s(b.z); v[7] = bf16s(b.w);
    return v;
}
// Layer-1 B fragment with the packed-h permutation: position 2c holds feature c,
// 2c+1 holds feature 16+c. k-chunk q covers features {4q..4q+3} x {16+4q..16+4q+3}.
static __device__ __forceinline__ s16x8 packW8sig(const float* __restrict__ row, int q) {
    const f32x4 lo = *(const f32x4*)(row + 4 * q);
    const f32x4 hi = *(const f32x4*)(row + 16 + 4 * q);
    s16x8 v;
    v[0] = bf16s(lo.x); v[1] = bf16s(hi.x); v[2] = bf16s(lo.y); v[3] = bf16s(hi.y);
    v[4] = bf16s(lo.z); v[5] = bf16s(hi.z); v[6] = bf16s(lo.w); v[7] = bf16s(hi.w);
    return v;
}

// ---------------------------------------------------------------------------
// All 11 hashed levels in ONE kernel, level-major block order (L2 locality
// preserved, dispatch tails overlapped). Even-x lanes fetch both x-corners
// with a single 16B-aligned float4 (PRIMES[0]==1 -> indices differ in bit 0).
// ---------------------------------------------------------------------------
__global__ __launch_bounds__(256) void hashed_all_kernel(
    const float* __restrict__ texc,
    const float* __restrict__ table,
    unsigned* __restrict__ enc_ws,
    int n, int B, HashParams P)
{
    __shared__ float tst[768];
    const int tid = threadIdx.x;
    const unsigned lvl = blockIdx.x / (unsigned)B;
    const unsigned blk = blockIdx.x - lvl * (unsigned)B;
    const int i0 = (int)blk * 256;

    tst[tid]       = __builtin_nontemporal_load(texc + 3 * i0 + tid);
    tst[tid + 256] = __builtin_nontemporal_load(texc + 3 * i0 + tid + 256);
    tst[tid + 512] = __builtin_nontemporal_load(texc + 3 * i0 + tid + 512);
    __syncthreads();

    const float s = P.scale[lvl];
    const float tx = tst[3 * tid + 0], ty = tst[3 * tid + 1], tz = tst[3 * tid + 2];

    const float px = tx * s + 0.5f, py = ty * s + 0.5f, pz = tz * s + 0.5f;
    const float gx = floorf(px), gy = floorf(py), gz = floorf(pz);
    const float wx = px - gx, wy = py - gy, wz = pz - gz;
    const unsigned x0 = (unsigned)gx, y0 = (unsigned)gy, z0 = (unsigned)gz;

    const unsigned hy0 = y0 * 2654435761u, hy1 = (y0 + 1u) * 2654435761u;
    const unsigned hz0 = z0 * 805459861u,  hz1 = (z0 + 1u) * 805459861u;
    const unsigned hh[4] = { hy0 ^ hz0, hy1 ^ hz0, hy0 ^ hz1, hy1 ^ hz1 };
    const float wyz[4] = { (1.f - wy) * (1.f - wz), wy * (1.f - wz),
                           (1.f - wy) * wz,         wy * wz };
    const float wx0 = 1.f - wx, wx1 = wx;

    const float* tbl = table + ((size_t)(N_DENSE + lvl) << 20); // 2^20 floats/level
    float f0 = 0.f, f1 = 0.f;

    if ((x0 & 1u) == 0u) {
#pragma unroll
        for (int c = 0; c < 4; ++c) {
            const unsigned idx0 = (x0 ^ hh[c]) & TMASK;
            const unsigned e = idx0 & ~1u;           // even -> 16B aligned pair
            const f32x4 g = *(const f32x4*)(tbl + 2 * (size_t)e);
            const bool hi = (idx0 & 1u) != 0u;       // which half is corner dx=0
            const float g0x = hi ? g.z : g.x, g0y = hi ? g.w : g.y;
            const float g1x = hi ? g.x : g.z, g1y = hi ? g.y : g.w;
            f0 += wyz[c] * (wx0 * g0x + wx1 * g1x);
            f1 += wyz[c] * (wx0 * g0y + wx1 * g1y);
        }
    } else {
#pragma unroll
        for (int c = 0; c < 4; ++c) {
            const unsigned ia = (x0 ^ hh[c]) & TMASK;
            const unsigned ib = ((x0 + 1u) ^ hh[c]) & TMASK;
            const f32x2 ga = *(const f32x2*)(tbl + 2 * (size_t)ia);
            const f32x2 gb = *(const f32x2*)(tbl + 2 * (size_t)ib);
            f0 += wyz[c] * (wx0 * ga.x + wx1 * gb.x);
            f1 += wyz[c] * (wx0 * ga.y + wx1 * gb.y);
        }
    }

    const unsigned packed = bf16_bits(f0) | (bf16_bits(f1) << 16);
    __builtin_nontemporal_store(packed, enc_ws + (size_t)lvl * n + (i0 + tid));
}

// ---------------------------------------------------------------------------
// Dense levels + MLP. Layers 0/1 on bf16 MFMA (per-wave [64x32]x[32x32]),
// layer 2 + sigmoid scalar. Per-wave private LDS slab (64 rows x 80 B), no
// barriers needed beyond the texc stage (same-wave LDS ops are ordered).
// ---------------------------------------------------------------------------
__global__ __launch_bounds__(256) void dense_mlp_kernel(
    const float* __restrict__ texc,
    const float* __restrict__ table,
    const unsigned* __restrict__ enc_ws,
    const float* __restrict__ W0,
    const float* __restrict__ W1,
    const float* __restrict__ W2,
    float* __restrict__ out,
    int n, DenseParams P)
{
    __shared__ float tst[768];
    __shared__ __align__(16) unsigned char slabs[4 * 64 * 80];
    const int tid = threadIdx.x;
    const int i0 = blockIdx.x * 256;

    tst[tid]       = __builtin_nontemporal_load(texc + 3 * i0 + tid);
    tst[tid + 256] = __builtin_nontemporal_load(texc + 3 * i0 + tid + 256);
    tst[tid + 512] = __builtin_nontemporal_load(texc + 3 * i0 + tid + 512);
    __syncthreads();

    const int i = i0 + tid;
    float enc[32];

    // Hashed features (coalesced streams)
#pragma unroll
    for (int l = 0; l < N_HASH; ++l) {
        const unsigned v = __builtin_nontemporal_load(enc_ws + (size_t)l * n + i);
        enc[2 * (l + N_DENSE) + 0] = bflo(v);
        enc[2 * (l + N_DENSE) + 1] = bfhi(v);
    }

    const float tx = tst[3 * tid + 0], ty = tst[3 * tid + 1], tz = tst[3 * tid + 2];

    // Dense levels 0..4 with x-pair loads when the pair is 16B aligned.
#pragma unroll
    for (int l = 0; l < N_DENSE; ++l) {
        const float s = P.scale[l];
        const unsigned res = P.res[l];
        const unsigned res2 = res * res;
        const float px = tx * s + 0.5f, py = ty * s + 0.5f, pz = tz * s + 0.5f;
        const float gx = floorf(px), gy = floorf(py), gz = floorf(pz);
        const float wx = px - gx, wy = py - gy, wz = pz - gz;
        const unsigned x0 = (unsigned)gx, y0 = (unsigned)gy, z0 = (unsigned)gz;
        const float wx0 = 1.f - wx, wx1 = wx;
        const float wyz[4] = { (1.f - wy) * (1.f - wz), wy * (1.f - wz),
                               (1.f - wy) * wz,         wy * wz };
        const unsigned base[4] = { y0 * res + z0 * res2, (y0 + 1u) * res + z0 * res2,
                                   y0 * res + (z0 + 1u) * res2,
                                   (y0 + 1u) * res + (z0 + 1u) * res2 };
        const float* tbl = table + ((size_t)l << 20);
        float f0 = 0.f, f1 = 0.f;
#pragma unroll
        for (int c = 0; c < 4; ++c) {
            const unsigned idx0 = x0 + base[c];
            if ((idx0 & 1u) == 0u) {
                const f32x4 g = *(const f32x4*)(tbl + 2 * (size_t)idx0);
                f0 += wyz[c] * (wx0 * g.x + wx1 * g.z);
                f1 += wyz[c] * (wx0 * g.y + wx1 * g.w);
            } else {
                const f32x2 ga = *(const f32x2*)(tbl + 2 * (size_t)idx0);
                const f32x2 gb = *(const f32x2*)(tbl + 2 * (size_t)(idx0 + 1u));
                f0 += wyz[c] * (wx0 * ga.x + wx1 * gb.x);
                f1 += wyz[c] * (wx0 * ga.y + wx1 * gb.y);
            }
        }
        enc[2 * l + 0] = f0;
        enc[2 * l + 1] = f1;
    }

    // ---- MFMA MLP ----
    const int lane = tid & 63;
    const int wv = tid >> 6;
    const int c16 = lane & 15, q = lane >> 4;
    unsigned char* slabB = slabs + wv * (64 * 80);
    unsigned* slab = (unsigned*)slabB;           // row stride 20 dwords (80 B)

    // stage enc -> bf16 rows (row = lane)
#pragma unroll
    for (int j = 0; j < 4; ++j) {
        s16x8 v;
#pragma unroll
        for (int jj = 0; jj < 8; ++jj) v[jj] = bf16s(enc[8 * j + jj]);
        *(s16x8*)(slabB + lane * 80 + 16 * j) = v;
    }

    // B fragments (in-register weight conversion; n = c16 (+16), k-chunk = q)
    const s16x8 b00 = packW8(W0 + c16 * 32 + 8 * q);
    const s16x8 b01 = packW8(W0 + (16 + c16) * 32 + 8 * q);
    const s16x8 b10 = packW8sig(W1 + c16 * 32, q);
    const s16x8 b11 = packW8sig(W1 + (16 + c16) * 32, q);
    const f32x4 zero4 = { 0.f, 0.f, 0.f, 0.f };

    // Layer 0
    f32x4 d0[4][2];
#pragma unroll
    for (int t = 0; t < 4; ++t) {
        const s16x8 a = *(const s16x8*)(slabB + (16 * t + c16) * 80 + 16 * q);
        d0[t][0] = __builtin_amdgcn_mfma_f32_16x16x32_bf16(a, b00, zero4, 0, 0, 0);
        d0[t][1] = __builtin_amdgcn_mfma_f32_16x16x32_bf16(a, b01, zero4, 0, 0, 0);
    }
    // relu + pack (positions 2c=feature c, 2c+1=feature 16+c) -> h1 in slab
#pragma unroll
    for (int t = 0; t < 4; ++t)
#pragma unroll
        for (int r = 0; r < 4; ++r) {
            const unsigned pk = bf16_bits(fmaxf(d0[t][0][r], 0.f)) |
                                (bf16_bits(fmaxf(d0[t][1][r], 0.f)) << 16);
            slab[(16 * t + 4 * q + r) * 20 + c16] = pk;
        }

    // Layer 1
    f32x4 d1[4][2];
#pragma unroll
    for (int t = 0; t < 4; ++t) {
        const s16x8 a = *(const s16x8*)(slabB + (16 * t + c16) * 80 + 16 * q);
        d1[t][0] = __builtin_amdgcn_mfma_f32_16x16x32_bf16(a, b10, zero4, 0, 0, 0);
        d1[t][1] = __builtin_amdgcn_mfma_f32_16x16x32_bf16(a, b11, zero4, 0, 0, 0);
    }
#pragma unroll
    for (int t = 0; t < 4; ++t)
#pragma unroll
        for (int r = 0; r < 4; ++r) {
            const unsigned pk = bf16_bits(fmaxf(d1[t][0][r], 0.f)) |
                                (bf16_bits(fmaxf(d1[t][1][r], 0.f)) << 16);
            slab[(16 * t + 4 * q + r) * 20 + c16] = pk;
        }

    // Layer 2 + sigmoid (scalar; dword d holds features d (lo) and 16+d (hi))
    float z0 = 0.f, z1 = 0.f, z2 = 0.f;
#pragma unroll
    for (int d = 0; d < 16; ++d) {
        const unsigned v = slab[lane * 20 + d];
        const float a0 = bflo(v), a1 = bfhi(v);
        z0 = fmaf(a0, W2[0 * 32 + d], fmaf(a1, W2[0 * 32 + 16 + d], z0));
        z1 = fmaf(a0, W2[1 * 32 + d], fmaf(a1, W2[1 * 32 + 16 + d], z1));
        z2 = fmaf(a0, W2[2 * 32 + d], fmaf(a1, W2[2 * 32 + 16 + d], z2));
    }
    out[3 * i + 0] = 1.f / (1.f + __expf(-z0));
    out[3 * i + 1] = 1.f / (1.f + __expf(-z1));
    out[3 * i + 2] = 1.f / (1.f + __expf(-z2));
}

// ---------------------------------------------------------------------------
// Fallback: monolithic kernel if ws too small or n % 256 != 0.
// ---------------------------------------------------------------------------
__global__ __launch_bounds__(256) void mono_kernel(
    const float* __restrict__ texc, const float* __restrict__ table,
    const float* __restrict__ W0, const float* __restrict__ W1,
    const float* __restrict__ W2, float* __restrict__ out, int n, AllParams p)
{
    int i = blockIdx.x * 256 + threadIdx.x;
    if (i >= n) return;
    const float tx = texc[3 * i], ty = texc[3 * i + 1], tz = texc[3 * i + 2];
    float enc[2 * NUM_LEVELS];
#pragma unroll
    for (int l = 0; l < NUM_LEVELS; ++l) {
        const float s = p.scale[l];
        const unsigned res = p.res[l];
        const float px = tx * s + 0.5f, py = ty * s + 0.5f, pz = tz * s + 0.5f;
        const float gx = floorf(px), gy = floorf(py), gz = floorf(pz);
        const float wx = px - gx, wy = py - gy, wz = pz - gz;
        const unsigned x0 = (unsigned)gx, y0 = (unsigned)gy, z0 = (unsigned)gz;
        const float2* tbl = (const float2*)(table + ((size_t)l << 20));
        float f0 = 0.f, f1 = 0.f;
#pragma unroll
        for (int c = 0; c < 8; ++c) {
            const unsigned dx = c & 1u, dy = (c >> 1) & 1u, dz = (c >> 2) & 1u;
            const unsigned xi = x0 + dx, yi = y0 + dy, zi = z0 + dz;
            unsigned idx;
            if (l < N_DENSE) idx = xi + yi * res + zi * res * res;
            else idx = (xi ^ (yi * 2654435761u) ^ (zi * 805459861u)) & TMASK;
            const float2 g = tbl[idx];
            const float w = (dx ? wx : 1.f - wx) * (dy ? wy : 1.f - wy) *
                            (dz ? wz : 1.f - wz);
            f0 = fmaf(w, g.x, f0);
            f1 = fmaf(w, g.y, f1);
        }
        enc[2 * l] = f0;
        enc[2 * l + 1] = f1;
    }
    float h1[32];
#pragma unroll
    for (int j = 0; j < 32; ++j) {
        float acc = 0.f;
#pragma unroll
        for (int k = 0; k < 32; ++k) acc = fmaf(enc[k], W0[j * 32 + k], acc);
        h1[j] = fmaxf(acc, 0.f);
    }
    float h2[32];
#pragma unroll
    for (int j = 0; j < 32; ++j) {
        float acc = 0.f;
#pragma unroll
        for (int k = 0; k < 32; ++k) acc = fmaf(h1[k], W1[j * 32 + k], acc);
        h2[j] = fmaxf(acc, 0.f);
    }
#pragma unroll
    for (int j = 0; j < 3; ++j) {
        float acc = 0.f;
#pragma unroll
        for (int k = 0; k < 32; ++k) acc = fmaf(h2[k], W2[j * 32 + k], acc);
        out[3 * i + j] = 1.f / (1.f + __expf(-acc));
    }
}

extern "C" void kernel_launch(void* const* d_in, const int* in_sizes, int n_in,
                              void* d_out, int out_size, void* d_ws, size_t ws_size,
                              hipStream_t stream) {
    const float* texc  = (const float*)d_in[0];
    const float* table = (const float*)d_in[1];
    const float* W0    = (const float*)d_in[2];
    const float* W1    = (const float*)d_in[3];
    const float* W2    = (const float*)d_in[4];
    float* out = (float*)d_out;

    const int n = in_sizes[0] / 3;

    AllParams ap;
    const double log2pls = log(4096.0 / 16.0) / 15.0 / log(2.0);
    for (int l = 0; l < NUM_LEVELS; ++l) {
        const double sc = exp2((double)l * log2pls) * 16.0 - 1.0;
        ap.scale[l] = (float)sc;
        ap.res[l] = (unsigned)(ceil(sc) + 1.0);
    }

    const size_t need = (size_t)N_HASH * (size_t)n * 4u;
    if ((n % 256) == 0 && ws_size >= need) {
        const int B = n / 256;
        HashParams hp;
        for (int l = 0; l < N_HASH; ++l) hp.scale[l] = ap.scale[l + N_DENSE];
        DenseParams dp;
        for (int l = 0; l < N_DENSE; ++l) { dp.scale[l] = ap.scale[l]; dp.res[l] = ap.res[l]; }

        hashed_all_kernel<<<B * N_HASH, 256, 0, stream>>>(
            texc, table, (unsigned*)d_ws, n, B, hp);
        dense_mlp_kernel<<<B, 256, 0, stream>>>(
            texc, table, (const unsigned*)d_ws, W0, W1, W2, out, n, dp);
    } else {
        const int blocks = (n + 255) / 256;
        mono_kernel<<<blocks, 256, 0, stream>>>(texc, table, W0, W1, W2, out, n, ap);
    }
}

// Round 5
// 1281.768 us; speedup vs baseline: 2.3421x; 1.1591x over previous
//
#include <hip/hip_runtime.h>
#include <math.h>

#define NUM_LEVELS 16
#define N_DENSE 5
#define N_HASH (NUM_LEVELS - N_DENSE)
#define TABLE_SIZE (1u << 19)
#define TMASK (TABLE_SIZE - 1u)

typedef float f32x4 __attribute__((ext_vector_type(4)));
typedef float f32x2 __attribute__((ext_vector_type(2)));
typedef short s16x8 __attribute__((ext_vector_type(8)));
typedef unsigned u32x2 __attribute__((ext_vector_type(2)));
typedef unsigned u32x4 __attribute__((ext_vector_type(4)));

struct HashParams { float scale[N_HASH]; };
struct DenseParams { float scale[N_DENSE]; unsigned res[N_DENSE]; };
struct AllParams { float scale[NUM_LEVELS]; unsigned res[NUM_LEVELS]; };

static __device__ __forceinline__ unsigned bf16_bits(float f) {
    const unsigned u = __builtin_bit_cast(unsigned, f);
    return (u + (0x7fffu + ((u >> 16) & 1u))) >> 16;
}
static __device__ __forceinline__ short bf16s(float f) { return (short)bf16_bits(f); }
static __device__ __forceinline__ float bflo(unsigned v) { return __builtin_bit_cast(float, v << 16); }
static __device__ __forceinline__ float bfhi(unsigned v) { return __builtin_bit_cast(float, v & 0xffff0000u); }

static __device__ __forceinline__ s16x8 packW8(const float* __restrict__ p) {
    const f32x4 a = *(const f32x4*)p;
    const f32x4 b = *(const f32x4*)(p + 4);
    s16x8 v;
    v[0] = bf16s(a.x); v[1] = bf16s(a.y); v[2] = bf16s(a.z); v[3] = bf16s(a.w);
    v[4] = bf16s(b.x); v[5] = bf16s(b.y); v[6] = bf16s(b.z); v[7] = bf16s(b.w);
    return v;
}
static __device__ __forceinline__ s16x8 packW8sig(const float* __restrict__ row, int q) {
    const f32x4 lo = *(const f32x4*)(row + 4 * q);
    const f32x4 hi = *(const f32x4*)(row + 16 + 4 * q);
    s16x8 v;
    v[0] = bf16s(lo.x); v[1] = bf16s(hi.x); v[2] = bf16s(lo.y); v[3] = bf16s(hi.y);
    v[4] = bf16s(lo.z); v[5] = bf16s(hi.z); v[6] = bf16s(lo.w); v[7] = bf16s(hi.w);
    return v;
}

// ---------------------------------------------------------------------------
// fp32 table -> packed bf16x2 table (1 dword/entry). 2 entries per thread.
// ---------------------------------------------------------------------------
__global__ __launch_bounds__(256) void cvt_table_kernel(
    const f32x4* __restrict__ src, u32x2* __restrict__ dst, int n2)
{
    const int i = blockIdx.x * 256 + threadIdx.x;
    if (i >= n2) return;
    const f32x4 g = __builtin_nontemporal_load(src + i);
    u32x2 o;
    o.x = bf16_bits(g.x) | (bf16_bits(g.y) << 16);
    o.y = bf16_bits(g.z) | (bf16_bits(g.w) << 16);
    dst[i] = o;
}

// ---------------------------------------------------------------------------
// All 11 hashed levels, level-major block order. BT: bf16 (dword) table.
// Even-x lanes fetch both x-corners with one aligned load (PRIMES[0]==1).
// ---------------------------------------------------------------------------
template <bool BT>
__global__ __launch_bounds__(256) void hashed_all_kernel(
    const float* __restrict__ texc,
    const float* __restrict__ tf,      // fp32 tables (BT=false)
    const unsigned* __restrict__ tb,   // bf16 tables (BT=true)
    unsigned* __restrict__ enc_ws,
    int n, int B, HashParams P)
{
    __shared__ float tst[768];
    const int tid = threadIdx.x;
    const unsigned lvl = blockIdx.x / (unsigned)B;
    const unsigned blk = blockIdx.x - lvl * (unsigned)B;
    const int i0 = (int)blk * 256;

    tst[tid]       = __builtin_nontemporal_load(texc + 3 * i0 + tid);
    tst[tid + 256] = __builtin_nontemporal_load(texc + 3 * i0 + tid + 256);
    tst[tid + 512] = __builtin_nontemporal_load(texc + 3 * i0 + tid + 512);
    __syncthreads();

    const float s = P.scale[lvl];
    const float tx = tst[3 * tid + 0], ty = tst[3 * tid + 1], tz = tst[3 * tid + 2];

    const float px = tx * s + 0.5f, py = ty * s + 0.5f, pz = tz * s + 0.5f;
    const float gx = floorf(px), gy = floorf(py), gz = floorf(pz);
    const float wx = px - gx, wy = py - gy, wz = pz - gz;
    const unsigned x0 = (unsigned)gx, y0 = (unsigned)gy, z0 = (unsigned)gz;

    const unsigned hy0 = y0 * 2654435761u, hy1 = (y0 + 1u) * 2654435761u;
    const unsigned hz0 = z0 * 805459861u,  hz1 = (z0 + 1u) * 805459861u;
    const unsigned hh[4] = { hy0 ^ hz0, hy1 ^ hz0, hy0 ^ hz1, hy1 ^ hz1 };
    const float wyz[4] = { (1.f - wy) * (1.f - wz), wy * (1.f - wz),
                           (1.f - wy) * wz,         wy * wz };
    const float wx0 = 1.f - wx, wx1 = wx;

    float f0 = 0.f, f1 = 0.f;

    if constexpr (BT) {
        const unsigned* tbl = tb + ((size_t)(N_DENSE + lvl) << 19);
        if ((x0 & 1u) == 0u) {
#pragma unroll
            for (int c = 0; c < 4; ++c) {
                const unsigned idx0 = (x0 ^ hh[c]) & TMASK;
                const u32x2 g = *(const u32x2*)(tbl + (idx0 & ~1u));
                const bool sw = (idx0 & 1u) != 0u;
                const unsigned ea = sw ? g.y : g.x;   // corner dx=0
                const unsigned eb = sw ? g.x : g.y;   // corner dx=1
                f0 += wyz[c] * (wx0 * bflo(ea) + wx1 * bflo(eb));
                f1 += wyz[c] * (wx0 * bfhi(ea) + wx1 * bfhi(eb));
            }
        } else {
#pragma unroll
            for (int c = 0; c < 4; ++c) {
                const unsigned ea = tbl[(x0 ^ hh[c]) & TMASK];
                const unsigned eb = tbl[((x0 + 1u) ^ hh[c]) & TMASK];
                f0 += wyz[c] * (wx0 * bflo(ea) + wx1 * bflo(eb));
                f1 += wyz[c] * (wx0 * bfhi(ea) + wx1 * bfhi(eb));
            }
        }
    } else {
        const float* tbl = tf + ((size_t)(N_DENSE + lvl) << 20);
        if ((x0 & 1u) == 0u) {
#pragma unroll
            for (int c = 0; c < 4; ++c) {
                const unsigned idx0 = (x0 ^ hh[c]) & TMASK;
                const f32x4 g = *(const f32x4*)(tbl + 2 * (size_t)(idx0 & ~1u));
                const bool hi = (idx0 & 1u) != 0u;
                const float g0x = hi ? g.z : g.x, g0y = hi ? g.w : g.y;
                const float g1x = hi ? g.x : g.z, g1y = hi ? g.y : g.w;
                f0 += wyz[c] * (wx0 * g0x + wx1 * g1x);
                f1 += wyz[c] * (wx0 * g0y + wx1 * g1y);
            }
        } else {
#pragma unroll
            for (int c = 0; c < 4; ++c) {
                const unsigned ia = (x0 ^ hh[c]) & TMASK;
                const unsigned ib = ((x0 + 1u) ^ hh[c]) & TMASK;
                const f32x2 ga = *(const f32x2*)(tbl + 2 * (size_t)ia);
                const f32x2 gb = *(const f32x2*)(tbl + 2 * (size_t)ib);
                f0 += wyz[c] * (wx0 * ga.x + wx1 * gb.x);
                f1 += wyz[c] * (wx0 * ga.y + wx1 * gb.y);
            }
        }
    }

    const unsigned packed = bf16_bits(f0) | (bf16_bits(f1) << 16);
    __builtin_nontemporal_store(packed, enc_ws + (size_t)lvl * n + (i0 + tid));
}

// ---------------------------------------------------------------------------
// Dense levels + MFMA MLP. Hashed enc dwords are already bf16x2 in A-layout
// order -> staged into the LDS slab directly (no unpack/repack).
// ---------------------------------------------------------------------------
template <bool BT>
__global__ __launch_bounds__(256) void dense_mlp_kernel(
    const float* __restrict__ texc,
    const float* __restrict__ tf,
    const unsigned* __restrict__ tb,
    const unsigned* __restrict__ enc_ws,
    const float* __restrict__ W0,
    const float* __restrict__ W1,
    const float* __restrict__ W2,
    float* __restrict__ out,
    int n, DenseParams P)
{
    __shared__ float tst[768];
    __shared__ __align__(16) unsigned char slabs[4 * 64 * 80];
    const int tid = threadIdx.x;
    const int i0 = blockIdx.x * 256;

    tst[tid]       = __builtin_nontemporal_load(texc + 3 * i0 + tid);
    tst[tid + 256] = __builtin_nontemporal_load(texc + 3 * i0 + tid + 256);
    tst[tid + 512] = __builtin_nontemporal_load(texc + 3 * i0 + tid + 512);
    __syncthreads();

    const int i = i0 + tid;
    unsigned dd[16];   // row of 16 bf16x2 dwords = enc[32]

    // Hashed features: 11 coalesced dword streams, already in final layout.
#pragma unroll
    for (int l = 0; l < N_HASH; ++l)
        dd[N_DENSE + l] = __builtin_nontemporal_load(enc_ws + (size_t)l * n + i);

    const float tx = tst[3 * tid + 0], ty = tst[3 * tid + 1], tz = tst[3 * tid + 2];

#pragma unroll
    for (int l = 0; l < N_DENSE; ++l) {
        const float s = P.scale[l];
        const unsigned res = P.res[l];
        const unsigned res2 = res * res;
        const float px = tx * s + 0.5f, py = ty * s + 0.5f, pz = tz * s + 0.5f;
        const float gx = floorf(px), gy = floorf(py), gz = floorf(pz);
        const float wx = px - gx, wy = py - gy, wz = pz - gz;
        const unsigned x0 = (unsigned)gx, y0 = (unsigned)gy, z0 = (unsigned)gz;
        const float wx0 = 1.f - wx, wx1 = wx;
        const float wyz[4] = { (1.f - wy) * (1.f - wz), wy * (1.f - wz),
                               (1.f - wy) * wz,         wy * wz };
        const unsigned base[4] = { y0 * res + z0 * res2, (y0 + 1u) * res + z0 * res2,
                                   y0 * res + (z0 + 1u) * res2,
                                   (y0 + 1u) * res + (z0 + 1u) * res2 };
        float f0 = 0.f, f1 = 0.f;
        if constexpr (BT) {
            const unsigned* tbl = tb + ((size_t)l << 19);
#pragma unroll
            for (int c = 0; c < 4; ++c) {
                const unsigned idx0 = x0 + base[c];
                unsigned ea, eb;
                if ((idx0 & 1u) == 0u) {
                    const u32x2 g = *(const u32x2*)(tbl + idx0);
                    ea = g.x; eb = g.y;
                } else {
                    ea = tbl[idx0]; eb = tbl[idx0 + 1u];
                }
                f0 += wyz[c] * (wx0 * bflo(ea) + wx1 * bflo(eb));
                f1 += wyz[c] * (wx0 * bfhi(ea) + wx1 * bfhi(eb));
            }
        } else {
            const float* tbl = tf + ((size_t)l << 20);
#pragma unroll
            for (int c = 0; c < 4; ++c) {
                const unsigned idx0 = x0 + base[c];
                if ((idx0 & 1u) == 0u) {
                    const f32x4 g = *(const f32x4*)(tbl + 2 * (size_t)idx0);
                    f0 += wyz[c] * (wx0 * g.x + wx1 * g.z);
                    f1 += wyz[c] * (wx0 * g.y + wx1 * g.w);
                } else {
                    const f32x2 ga = *(const f32x2*)(tbl + 2 * (size_t)idx0);
                    const f32x2 gb = *(const f32x2*)(tbl + 2 * (size_t)(idx0 + 1u));
                    f0 += wyz[c] * (wx0 * ga.x + wx1 * gb.x);
                    f1 += wyz[c] * (wx0 * ga.y + wx1 * gb.y);
                }
            }
        }
        dd[l] = bf16_bits(f0) | (bf16_bits(f1) << 16);
    }

    // ---- MFMA MLP ----
    const int lane = tid & 63;
    const int wv = tid >> 6;
    const int c16 = lane & 15, q = lane >> 4;
    unsigned char* slabB = slabs + wv * (64 * 80);
    unsigned* slab = (unsigned*)slabB;   // row stride 20 dwords (80 B)

    *(u32x4*)(slabB + lane * 80 +  0) = (u32x4){ dd[0],  dd[1],  dd[2],  dd[3]  };
    *(u32x4*)(slabB + lane * 80 + 16) = (u32x4){ dd[4],  dd[5],  dd[6],  dd[7]  };
    *(u32x4*)(slabB + lane * 80 + 32) = (u32x4){ dd[8],  dd[9],  dd[10], dd[11] };
    *(u32x4*)(slabB + lane * 80 + 48) = (u32x4){ dd[12], dd[13], dd[14], dd[15] };

    const s16x8 b00 = packW8(W0 + c16 * 32 + 8 * q);
    const s16x8 b01 = packW8(W0 + (16 + c16) * 32 + 8 * q);
    const s16x8 b10 = packW8sig(W1 + c16 * 32, q);
    const s16x8 b11 = packW8sig(W1 + (16 + c16) * 32, q);
    const f32x4 zero4 = { 0.f, 0.f, 0.f, 0.f };

    f32x4 d0[4][2];
#pragma unroll
    for (int t = 0; t < 4; ++t) {
        const s16x8 a = *(const s16x8*)(slabB + (16 * t + c16) * 80 + 16 * q);
        d0[t][0] = __builtin_amdgcn_mfma_f32_16x16x32_bf16(a, b00, zero4, 0, 0, 0);
        d0[t][1] = __builtin_amdgcn_mfma_f32_16x16x32_bf16(a, b01, zero4, 0, 0, 0);
    }
#pragma unroll
    for (int t = 0; t < 4; ++t)
#pragma unroll
        for (int r = 0; r < 4; ++r) {
            const unsigned pk = bf16_bits(fmaxf(d0[t][0][r], 0.f)) |
                                (bf16_bits(fmaxf(d0[t][1][r], 0.f)) << 16);
            slab[(16 * t + 4 * q + r) * 20 + c16] = pk;
        }

    f32x4 d1[4][2];
#pragma unroll
    for (int t = 0; t < 4; ++t) {
        const s16x8 a = *(const s16x8*)(slabB + (16 * t + c16) * 80 + 16 * q);
        d1[t][0] = __builtin_amdgcn_mfma_f32_16x16x32_bf16(a, b10, zero4, 0, 0, 0);
        d1[t][1] = __builtin_amdgcn_mfma_f32_16x16x32_bf16(a, b11, zero4, 0, 0, 0);
    }
#pragma unroll
    for (int t = 0; t < 4; ++t)
#pragma unroll
        for (int r = 0; r < 4; ++r) {
            const unsigned pk = bf16_bits(fmaxf(d1[t][0][r], 0.f)) |
                                (bf16_bits(fmaxf(d1[t][1][r], 0.f)) << 16);
            slab[(16 * t + 4 * q + r) * 20 + c16] = pk;
        }

    float z0 = 0.f, z1 = 0.f, z2 = 0.f;
#pragma unroll
    for (int d = 0; d < 16; ++d) {
        const unsigned v = slab[lane * 20 + d];
        const float a0 = bflo(v), a1 = bfhi(v);
        z0 = fmaf(a0, W2[0 * 32 + d], fmaf(a1, W2[0 * 32 + 16 + d], z0));
        z1 = fmaf(a0, W2[1 * 32 + d], fmaf(a1, W2[1 * 32 + 16 + d], z1));
        z2 = fmaf(a0, W2[2 * 32 + d], fmaf(a1, W2[2 * 32 + 16 + d], z2));
    }
    out[3 * i + 0] = 1.f / (1.f + __expf(-z0));
    out[3 * i + 1] = 1.f / (1.f + __expf(-z1));
    out[3 * i + 2] = 1.f / (1.f + __expf(-z2));
}

// ---------------------------------------------------------------------------
// Fallback: monolithic kernel.
// ---------------------------------------------------------------------------
__global__ __launch_bounds__(256) void mono_kernel(
    const float* __restrict__ texc, const float* __restrict__ table,
    const float* __restrict__ W0, const float* __restrict__ W1,
    const float* __restrict__ W2, float* __restrict__ out, int n, AllParams p)
{
    int i = blockIdx.x * 256 + threadIdx.x;
    if (i >= n) return;
    const float tx = texc[3 * i], ty = texc[3 * i + 1], tz = texc[3 * i + 2];
    float enc[2 * NUM_LEVELS];
#pragma unroll
    for (int l = 0; l < NUM_LEVELS; ++l) {
        const float s = p.scale[l];
        const unsigned res = p.res[l];
        const float px = tx * s + 0.5f, py = ty * s + 0.5f, pz = tz * s + 0.5f;
        const float gx = floorf(px), gy = floorf(py), gz = floorf(pz);
        const float wx = px - gx, wy = py - gy, wz = pz - gz;
        const unsigned x0 = (unsigned)gx, y0 = (unsigned)gy, z0 = (unsigned)gz;
        const float2* tbl = (const float2*)(table + ((size_t)l << 20));
        float f0 = 0.f, f1 = 0.f;
#pragma unroll
        for (int c = 0; c < 8; ++c) {
            const unsigned dx = c & 1u, dy = (c >> 1) & 1u, dz = (c >> 2) & 1u;
            const unsigned xi = x0 + dx, yi = y0 + dy, zi = z0 + dz;
            unsigned idx;
            if (l < N_DENSE) idx = xi + yi * res + zi * res * res;
            else idx = (xi ^ (yi * 2654435761u) ^ (zi * 805459861u)) & TMASK;
            const float2 g = tbl[idx];
            const float w = (dx ? wx : 1.f - wx) * (dy ? wy : 1.f - wy) *
                            (dz ? wz : 1.f - wz);
            f0 = fmaf(w, g.x, f0);
            f1 = fmaf(w, g.y, f1);
        }
        enc[2 * l] = f0;
        enc[2 * l + 1] = f1;
    }
    float h1[32];
#pragma unroll
    for (int j = 0; j < 32; ++j) {
        float acc = 0.f;
#pragma unroll
        for (int k = 0; k < 32; ++k) acc = fmaf(enc[k], W0[j * 32 + k], acc);
        h1[j] = fmaxf(acc, 0.f);
    }
    float h2[32];
#pragma unroll
    for (int j = 0; j < 32; ++j) {
        float acc = 0.f;
#pragma unroll
        for (int k = 0; k < 32; ++k) acc = fmaf(h1[k], W1[j * 32 + k], acc);
        h2[j] = fmaxf(acc, 0.f);
    }
#pragma unroll
    for (int j = 0; j < 3; ++j) {
        float acc = 0.f;
#pragma unroll
        for (int k = 0; k < 32; ++k) acc = fmaf(h2[k], W2[j * 32 + k], acc);
        out[3 * i + j] = 1.f / (1.f + __expf(-acc));
    }
}

extern "C" void kernel_launch(void* const* d_in, const int* in_sizes, int n_in,
                              void* d_out, int out_size, void* d_ws, size_t ws_size,
                              hipStream_t stream) {
    const float* texc  = (const float*)d_in[0];
    const float* table = (const float*)d_in[1];
    const float* W0    = (const float*)d_in[2];
    const float* W1    = (const float*)d_in[3];
    const float* W2    = (const float*)d_in[4];
    float* out = (float*)d_out;

    const int n = in_sizes[0] / 3;

    AllParams ap;
    const double log2pls = log(4096.0 / 16.0) / 15.0 / log(2.0);
    for (int l = 0; l < NUM_LEVELS; ++l) {
        const double sc = exp2((double)l * log2pls) * 16.0 - 1.0;
        ap.scale[l] = (float)sc;
        ap.res[l] = (unsigned)(ceil(sc) + 1.0);
    }
    HashParams hp;
    for (int l = 0; l < N_HASH; ++l) hp.scale[l] = ap.scale[l + N_DENSE];
    DenseParams dp;
    for (int l = 0; l < N_DENSE; ++l) { dp.scale[l] = ap.scale[l]; dp.res[l] = ap.res[l]; }

    const size_t enc_b = (size_t)N_HASH * (size_t)n * 4u;
    const size_t tbl_b = (size_t)NUM_LEVELS * TABLE_SIZE * 4u;   // 32 MiB bf16 tables

    if ((n % 256) == 0 && ws_size >= tbl_b + enc_b) {
        unsigned* bt = (unsigned*)d_ws;
        unsigned* enc_ws = bt + (size_t)NUM_LEVELS * TABLE_SIZE;
        const int B = n / 256;
        const int n2 = NUM_LEVELS * TABLE_SIZE / 2;
        cvt_table_kernel<<<(n2 + 255) / 256, 256, 0, stream>>>(
            (const f32x4*)table, (u32x2*)bt, n2);
        hashed_all_kernel<true><<<B * N_HASH, 256, 0, stream>>>(
            texc, table, bt, enc_ws, n, B, hp);
        dense_mlp_kernel<true><<<B, 256, 0, stream>>>(
            texc, table, bt, enc_ws, W0, W1, W2, out, n, dp);
    } else if ((n % 256) == 0 && ws_size >= enc_b) {
        unsigned* enc_ws = (unsigned*)d_ws;
        const int B = n / 256;
        hashed_all_kernel<false><<<B * N_HASH, 256, 0, stream>>>(
            texc, table, nullptr, enc_ws, n, B, hp);
        dense_mlp_kernel<false><<<B, 256, 0, stream>>>(
            texc, table, nullptr, enc_ws, W0, W1, W2, out, n, dp);
    } else {
        const int blocks = (n + 255) / 256;
        mono_kernel<<<blocks, 256, 0, stream>>>(texc, table, W0, W1, W2, out, n, ap);
    }
}